// Round 18
// baseline (81.703 us; speedup 1.0000x reference)
//
#include <hip/hip_runtime.h>
#include <hip/hip_bf16.h>

// Fused GATConv + proj + LayerNorm + ReLU. N=50000, E=800000, F_IN=128, H=4, C=16, D=128.
// CSR build is ATOMIC-FREE at global scope (global atomics = 19G/s wall, rounds 6/8/9).
// CHUNK=2048 (8192 regressed: coarser interleave tail > write-combining gain, round 16).
//   k_prep_part1 : FUSED: per-chunk LDS histogram of dst>>8 + weight packing
//   k_scanB1     : per-bucket column scan over chunks -> per-(chunk,bucket) prefix + bt[]
//   k_part2_xw   : FUSED: (a) scatter edges into bucket runs, (b) xp = x@W split-bf16 MFMA
//   k_csr        : per bucket: bb from bt (LDS scan) + exact-node histogram -> row_ptr/colsrc
//   k_agg_proj   : FUSED agg+proj+LN+ReLU (2x-unrolled gather, launch_bounds(256,8):
//                  latency-bound gather -> max TLP, 32 waves/CU; VGPR must stay <=64)

#define LEAKY(x) ((x) > 0.f ? (x) : 0.2f * (x))
#define CHUNK 2048
#define NBUK_PAD 256

typedef __attribute__((ext_vector_type(8))) short bf16x8;
typedef __attribute__((ext_vector_type(8))) unsigned short u16x8;
typedef __attribute__((ext_vector_type(4))) float f32x4;

static __device__ __forceinline__ unsigned short f2bf_rne(float f) {
    unsigned u = __float_as_uint(f);
    return (unsigned short)((u + 0x7FFFu + ((u >> 16) & 1u)) >> 16);
}
static __device__ __forceinline__ float bf2f(unsigned short h) {
    return __uint_as_float(((unsigned)h) << 16);
}

// bid < nchunk: LDS histogram of one CHUNK-edge range by dst>>8. bid >= nchunk: weight packing.
__global__ __launch_bounds__(256) void k_prep_part1(
    const float* __restrict__ W, const float* __restrict__ bias,
    const float* __restrict__ proj_w, const float* __restrict__ proj_b,
    unsigned short* __restrict__ Whf, unsigned short* __restrict__ Wlf,
    unsigned short* __restrict__ Phf, unsigned short* __restrict__ Plf,
    float* __restrict__ pb2,
    const int* __restrict__ dst, int* __restrict__ cnt, int E, int nchunk)
{
    int bid = blockIdx.x, t = threadIdx.x;
    if (bid < nchunk) {
        __shared__ int hist[NBUK_PAD];
        hist[t] = 0;
        __syncthreads();
        int e0 = bid * CHUNK;
#pragma unroll
        for (int i = 0; i < CHUNK / 256; i++) {
            int e = e0 + i * 256 + t;
            if (e < E) atomicAdd(&hist[dst[e] >> 8], 1);   // LDS atomic
        }
        __syncthreads();
        cnt[bid * NBUK_PAD + t] = hist[t];
        return;
    }
    int idx = (bid - nchunk) * 256 + t;
    if (idx < 8192) {
        int j = idx & 7, lane = (idx >> 3) & 63, ts = idx >> 9;
        int tt = ts >> 2, s = ts & 3;
        int k = s * 32 + ((lane >> 4) << 3) + j;
        int n = tt * 16 + (lane & 15);
        float w = W[k * 64 + n];
        unsigned short wh = f2bf_rne(w);
        Whf[idx] = wh;
        Wlf[idx] = f2bf_rne(w - bf2f(wh));
    } else if (idx < 16384) {
        int i2 = idx - 8192;
        int j = i2 & 7, lane = (i2 >> 3) & 63, ts = i2 >> 9;
        int tt = ts >> 1, s = ts & 1;
        int k = s * 32 + ((lane >> 4) << 3) + j;
        int d = tt * 16 + (lane & 15);
        float w = proj_w[d * 64 + k];
        unsigned short wh = f2bf_rne(w);
        Phf[i2] = wh;
        Plf[i2] = f2bf_rne(w - bf2f(wh));
    } else if (idx < 16384 + 128) {
        int d = idx - 16384;
        float s = proj_b[d];
        for (int j = 0; j < 64; j++) s += bias[j] * proj_w[d * 64 + j];
        pb2[d] = s;
    }
}

// Per-bucket column scan over chunks (nchunk <= 512). Emits bucket totals bt[].
__global__ __launch_bounds__(256) void k_scanB1(int* __restrict__ cnt, int* __restrict__ bt,
                                                int* __restrict__ row_ptr,
                                                int nchunk, int n_nodes, int E)
{
    __shared__ int sh[256];
    int t = threadIdx.x, b = blockIdx.x;
    int v0 = (t < nchunk) ? cnt[t * NBUK_PAD + b] : 0;
    int v1 = (t + 256 < nchunk) ? cnt[(t + 256) * NBUK_PAD + b] : 0;
    sh[t] = v0; __syncthreads();
    for (int off = 1; off < 256; off <<= 1) {
        int u = (t >= off) ? sh[t - off] : 0;
        __syncthreads();
        sh[t] += u;
        __syncthreads();
    }
    int incl0 = sh[t], tot0 = sh[255];
    __syncthreads();
    sh[t] = v1; __syncthreads();
    for (int off = 1; off < 256; off <<= 1) {
        int u = (t >= off) ? sh[t - off] : 0;
        __syncthreads();
        sh[t] += u;
        __syncthreads();
    }
    int incl1 = sh[t] + tot0;
    if (t < nchunk) cnt[t * NBUK_PAD + b] = incl0 - v0;
    if (t + 256 < nchunk) cnt[(t + 256) * NBUK_PAD + b] = incl1 - v1;
    if (t == 255) bt[b] = incl1;
    if (b == 0 && t == 0) row_ptr[n_nodes] = E;
}

// FUSED part2 + xw. Every P-th block scatters one CHUNK-edge range into bucket runs
// (bucket bases re-derived from bt via LDS scan); other blocks do a 64-node xw tile.
__global__ __launch_bounds__(256) void k_part2_xw(
    const int* __restrict__ src, const int* __restrict__ dst,
    const int* __restrict__ cnt, const int* __restrict__ bt,
    unsigned* __restrict__ part, int E,
    const float* __restrict__ x,
    const unsigned short* __restrict__ Whf, const unsigned short* __restrict__ Wlf,
    const float* __restrict__ att_src, const float* __restrict__ att_dst,
    unsigned short* __restrict__ xp, float* __restrict__ a_src, float* __restrict__ a_dst,
    int n_nodes, int P, int nbXw)
{
    __shared__ float xs[64][132];          // 33.8 KB (xw path)
    __shared__ int bases[NBUK_PAD];        // part2 path
    __shared__ int sh[256];
    int bid = blockIdx.x, t = threadIdx.x;
    if (bid % P == P - 1) {
        int blk = bid / P;
        int v = bt[t];
        sh[t] = v; __syncthreads();
        for (int off = 1; off < 256; off <<= 1) {
            int u = (t >= off) ? sh[t - off] : 0;
            __syncthreads();
            sh[t] += u;
            __syncthreads();
        }
        bases[t] = cnt[blk * NBUK_PAD + t] + (sh[t] - v);
        __syncthreads();
        int e0 = blk * CHUNK;
#pragma unroll
        for (int i = 0; i < CHUNK / 256; i++) {
            int e = e0 + i * 256 + t;
            if (e < E) {
                int d = dst[e];
                int s = src[e];
                int pos = atomicAdd(&bases[d >> 8], 1);   // LDS atomic
                part[pos] = ((unsigned)s << 8) | (unsigned)(d & 255);
            }
        }
        return;
    }
    // ---- xw path ----
    int xb = bid - bid / P;
    if (xb >= nbXw) return;
    int xbase = xb * 64;
    for (int i = t; i < 64 * 32; i += 256) {
        int r = i >> 5, c = (i & 31) << 2;
        int gr = xbase + r; if (gr >= n_nodes) gr = n_nodes - 1;
        *(float4*)&xs[r][c] = *(const float4*)(x + (size_t)gr * 128 + c);
    }
    __syncthreads();
    int w = t >> 6, lane = t & 63;
    int mbase = xbase + w * 16;
    int mrow = lane & 15, kg = lane >> 4;
    int lrow = w * 16 + mrow;

    bf16x8 ah[4], al[4];
#pragma unroll
    for (int s = 0; s < 4; s++) {
        float4 v0 = *(const float4*)&xs[lrow][s * 32 + kg * 8];
        float4 v1 = *(const float4*)&xs[lrow][s * 32 + kg * 8 + 4];
        float f[8] = {v0.x, v0.y, v0.z, v0.w, v1.x, v1.y, v1.z, v1.w};
#pragma unroll
        for (int j = 0; j < 8; j++) {
            unsigned short h = f2bf_rne(f[j]);
            ah[s][j] = (short)h;
            al[s][j] = (short)f2bf_rne(f[j] - bf2f(h));
        }
    }

    f32x4 acc[4];
#pragma unroll
    for (int tt = 0; tt < 4; tt++) acc[tt] = (f32x4){0.f, 0.f, 0.f, 0.f};
#pragma unroll
    for (int tt = 0; tt < 4; tt++) {
#pragma unroll
        for (int s = 0; s < 4; s++) {
            size_t fi = (size_t)(((tt * 4 + s) * 64 + lane) * 8);
            bf16x8 bh = *(const bf16x8*)(Whf + fi);
            bf16x8 bl = *(const bf16x8*)(Wlf + fi);
            acc[tt] = __builtin_amdgcn_mfma_f32_16x16x32_bf16(ah[s], bh, acc[tt], 0, 0, 0);
            acc[tt] = __builtin_amdgcn_mfma_f32_16x16x32_bf16(ah[s], bl, acc[tt], 0, 0, 0);
            acc[tt] = __builtin_amdgcn_mfma_f32_16x16x32_bf16(al[s], bh, acc[tt], 0, 0, 0);
        }
    }

    // D layout: col=lane&15, row=(lane>>4)*4+reg. Tile tt == head tt.
#pragma unroll
    for (int tt = 0; tt < 4; tt++) {
        float asv = att_src[tt * 16 + mrow];
        float adv = att_dst[tt * 16 + mrow];
#pragma unroll
        for (int r = 0; r < 4; r++) {
            float v = acc[tt][r];
            int n2 = mbase + kg * 4 + r;
            bool ok = (n2 < n_nodes);
            if (ok) xp[(size_t)n2 * 64 + tt * 16 + mrow] = f2bf_rne(v);
            float ts = v * asv;
            float td = v * adv;
#pragma unroll
            for (int off = 8; off; off >>= 1) {
                ts += __shfl_xor(ts, off);
                td += __shfl_xor(td, off);
            }
            if (mrow == 0 && ok) {
                a_src[n2 * 4 + tt] = ts;
                a_dst[n2 * 4 + tt] = td;
            }
        }
    }
}

// One block per bucket: bb from bt (LDS scan), exact-node histogram + scan -> row_ptr/colsrc.
__global__ __launch_bounds__(256) void k_csr(const unsigned* __restrict__ part, const int* __restrict__ bt,
                                             int* __restrict__ row_ptr, int* __restrict__ colsrc,
                                             int n_nodes)
{
    __shared__ int hist[256], off[256], sh[256];
    int t = threadIdx.x, b = blockIdx.x;
    int v = bt[t];
    sh[t] = v; __syncthreads();
    for (int o = 1; o < 256; o <<= 1) {
        int u = (t >= o) ? sh[t - o] : 0;
        __syncthreads();
        sh[t] += u;
        __syncthreads();
    }
    int e0 = (b > 0) ? sh[b - 1] : 0;
    int e1 = sh[b];
    __syncthreads();
    int m = e1 - e0;
    hist[t] = 0;
    __syncthreads();
    for (int i = t; i < m; i += 256)
        atomicAdd(&hist[part[e0 + i] & 255u], 1);     // LDS atomic
    __syncthreads();
    int hv = hist[t];
    sh[t] = hv; __syncthreads();
    for (int o = 1; o < 256; o <<= 1) {
        int u = (t >= o) ? sh[t - o] : 0;
        __syncthreads();
        sh[t] += u;
        __syncthreads();
    }
    int excl = sh[t] - hv;
    off[t] = excl;
    int node = b * 256 + t;
    if (node < n_nodes) row_ptr[node] = e0 + excl;
    __syncthreads();
    for (int i = t; i < m; i += 256) {
        unsigned u = part[e0 + i];
        int pos = atomicAdd(&off[u & 255u], 1);       // LDS atomic
        colsrc[e0 + pos] = (int)(u >> 8);
    }
}

// FUSED aggregation + projection + LayerNorm + ReLU. Block = 16 nodes, 4 waves.
// Phase 1 (per wave): 4 nodes, one at a time; gather loop 2x-unrolled (two u16x8 loads
//   in flight). launch_bounds(256,8): latency-bound -> 32 waves/CU.
// Phase 2: proj d-tiles split across waves (2 each, 8 MFMA/wave), LN via cross-wave
//   LDS partials, ReLU, store.
__global__ __launch_bounds__(256, 8) void k_agg_proj(
    const unsigned short* __restrict__ xp, const float* __restrict__ a_src, const float* __restrict__ a_dst,
    const int* __restrict__ row_ptr, const int* __restrict__ colsrc,
    const unsigned short* __restrict__ Phf, const unsigned short* __restrict__ Plf,
    const float* __restrict__ pb2, const float* __restrict__ gamma, const float* __restrict__ beta,
    float* __restrict__ out, int n_nodes)
{
    __shared__ int   sstage[4][64];            // 1 KB
    __shared__ float alpha_s[4][64][4];        // 4 KB
    __shared__ unsigned short rowbuf[16][72];  // 2.25 KB (144B rows, 16B aligned)
    __shared__ float pS[4][16], pQ[4][16];     // 0.5 KB
    __shared__ float pb_s[128], g_s[128], b_s[128];
    int t = threadIdx.x, w = t >> 6, lane = t & 63;
    if (t < 128) { pb_s[t] = pb2[t]; g_s[t] = gamma[t]; b_s[t] = beta[t]; }
    int cgrp = lane & 7;      // channels 8*cgrp .. 8*cgrp+7
    int eoct = lane >> 3;     // edge slot 0..7
    int h = cgrp >> 1;        // head of my 8 channels
    int nb16 = blockIdx.x * 16;

    // ---- phase 1: aggregate 4 nodes per wave ----
    for (int i = 0; i < 4; i++) {
        int n = nb16 + w * 4 + i;
        int nl = w * 4 + i;
        float acc[8] = {0.f,0.f,0.f,0.f,0.f,0.f,0.f,0.f};
        float den = 0.f;
        if (n < n_nodes) {
            int rp0 = row_ptr[n], rp1 = row_ptr[n + 1];
            float4 ad4 = *(const float4*)&a_dst[(size_t)n * 4];
            for (int base = rp0; base < rp1; base += 64) {
                int cnt = rp1 - base; if (cnt > 64) cnt = 64;
                int s = 0;
                float4 p = make_float4(0.f, 0.f, 0.f, 0.f);
                if (lane < cnt) {
                    s = colsrc[base + lane];
                    float4 as4 = *(const float4*)&a_src[(size_t)s * 4];
                    p.x = __expf(LEAKY(as4.x + ad4.x));
                    p.y = __expf(LEAKY(as4.y + ad4.y));
                    p.z = __expf(LEAKY(as4.z + ad4.z));
                    p.w = __expf(LEAKY(as4.w + ad4.w));
                }
                sstage[w][lane] = s;
                *(float4*)&alpha_s[w][lane][0] = p;
                // same-wave LDS write->read is in-order; no barrier needed
                int iters = (cnt + 7) >> 3;
                int it = 0;
                // 2x unroll: issue both gathers before consuming either (2x MLP).
                for (; it + 2 <= iters; it += 2) {
                    int j0 = (it << 3) + eoct;
                    int j1 = j0 + 8;
                    int sj0 = sstage[w][j0];
                    int sj1 = sstage[w][j1];
                    float aj0 = alpha_s[w][j0][h];
                    float aj1 = alpha_s[w][j1][h];
                    u16x8 v0 = *(const u16x8*)(xp + (size_t)((unsigned)sj0 * 64u + (cgrp << 3)));
                    u16x8 v1 = *(const u16x8*)(xp + (size_t)((unsigned)sj1 * 64u + (cgrp << 3)));
                    den += aj0;
#pragma unroll
                    for (int q = 0; q < 8; q++) acc[q] += aj0 * bf2f(v0[q]);
                    den += aj1;
#pragma unroll
                    for (int q = 0; q < 8; q++) acc[q] += aj1 * bf2f(v1[q]);
                }
                if (it < iters) {
                    int j = (it << 3) + eoct;
                    int sj = sstage[w][j];
                    float aj = alpha_s[w][j][h];
                    u16x8 v = *(const u16x8*)(xp + (size_t)((unsigned)sj * 64u + (cgrp << 3)));
                    den += aj;
#pragma unroll
                    for (int q = 0; q < 8; q++) acc[q] += aj * bf2f(v[q]);
                }
            }
#pragma unroll
            for (int q = 0; q < 8; q++) {
                acc[q] += __shfl_xor(acc[q], 8);
                acc[q] += __shfl_xor(acc[q], 16);
                acc[q] += __shfl_xor(acc[q], 32);
            }
            den += __shfl_xor(den, 8);
            den += __shfl_xor(den, 16);
            den += __shfl_xor(den, 32);
        }
        if (eoct == 0) {
            float inv = 1.f / (den + 1e-16f);
            u16x8 o;
#pragma unroll
            for (int q = 0; q < 8; q++) o[q] = f2bf_rne(acc[q] * inv);
            *(u16x8*)&rowbuf[nl][cgrp << 3] = o;
        }
    }
    __syncthreads();

    // ---- phase 2: projection. wave w covers d-tiles {2w, 2w+1} for all 16 nodes ----
    int mrow = lane & 15, kg = lane >> 4;
    bf16x8 ah[2];
#pragma unroll
    for (int s = 0; s < 2; s++) {
        ah[s] = *(const bf16x8*)&rowbuf[mrow][s * 32 + kg * 8];
    }
    f32x4 acc2[2];
#pragma unroll
    for (int ttl = 0; ttl < 2; ttl++) acc2[ttl] = (f32x4){0.f, 0.f, 0.f, 0.f};
#pragma unroll
    for (int ttl = 0; ttl < 2; ttl++) {
        int tt = w * 2 + ttl;
#pragma unroll
        for (int s = 0; s < 2; s++) {
            size_t fi = (size_t)(((tt * 2 + s) * 64 + lane) * 8);
            bf16x8 bh = *(const bf16x8*)(Phf + fi);
            bf16x8 bl = *(const bf16x8*)(Plf + fi);
            acc2[ttl] = __builtin_amdgcn_mfma_f32_16x16x32_bf16(ah[s], bh, acc2[ttl], 0, 0, 0);
            acc2[ttl] = __builtin_amdgcn_mfma_f32_16x16x32_bf16(ah[s], bl, acc2[ttl], 0, 0, 0);
        }
    }
    // D layout: node_row = kg*4 + r, d = tt*16 + mrow. LN partials per node over this
    // wave's 32 d-channels; cross-wave combine via LDS.
    float vv[2][4];
#pragma unroll
    for (int r = 0; r < 4; r++) {
        float S = 0.f, Q = 0.f;
#pragma unroll
        for (int ttl = 0; ttl < 2; ttl++) {
            int tt = w * 2 + ttl;
            float v = acc2[ttl][r] + pb_s[tt * 16 + mrow];
            vv[ttl][r] = v;
            S += v;
            Q += v * v;
        }
#pragma unroll
        for (int off = 8; off; off >>= 1) {
            S += __shfl_xor(S, off);
            Q += __shfl_xor(Q, off);
        }
        if (mrow == 0) { pS[w][kg * 4 + r] = S; pQ[w][kg * 4 + r] = Q; }
    }
    __syncthreads();
#pragma unroll
    for (int r = 0; r < 4; r++) {
        int nl = kg * 4 + r;
        int nr = nb16 + nl;
        float S = pS[0][nl] + pS[1][nl] + pS[2][nl] + pS[3][nl];
        float Q = pQ[0][nl] + pQ[1][nl] + pQ[2][nl] + pQ[3][nl];
        float mu  = S * (1.f / 128.f);
        float var = Q * (1.f / 128.f) - mu * mu;
        float inv = rsqrtf(var + 1e-5f);
        if (nr < n_nodes) {
#pragma unroll
            for (int ttl = 0; ttl < 2; ttl++) {
                int d = (w * 2 + ttl) * 16 + mrow;
                float o = fmaxf((vv[ttl][r] - mu) * inv * g_s[d] + b_s[d], 0.f);
                out[(size_t)nr * 128 + d] = o;
            }
        }
    }
}

extern "C" void kernel_launch(void* const* d_in, const int* in_sizes, int n_in,
                              void* d_out, int out_size, void* d_ws, size_t ws_size,
                              hipStream_t stream)
{
    const float* x       = (const float*)d_in[0];
    const int*   ei      = (const int*)  d_in[1];
    const float* W       = (const float*)d_in[2];
    const float* att_src = (const float*)d_in[3];
    const float* att_dst = (const float*)d_in[4];
    const float* bias    = (const float*)d_in[5];
    const float* proj_w  = (const float*)d_in[6];
    const float* proj_b  = (const float*)d_in[7];
    const float* gamma   = (const float*)d_in[8];
    const float* beta    = (const float*)d_in[9];

    int N = in_sizes[0] / 128;
    int E = in_sizes[1] / 2;
    const int* srcIdx = ei;
    const int* dstIdx = ei + E;

    int nchunk = (E + CHUNK - 1) / CHUNK;          // edge chunks
    int NBUK   = (N + 255) / 256;                  // node buckets
    int nbXw   = (N + 63) / 64;
    int nbPrep = (16512 + 255) / 256;

    char* ws = (char*)d_ws;
    unsigned short* xp = (unsigned short*)ws; ws += (size_t)N * 64 * 2;
    float* a_src   = (float*)ws; ws += (size_t)N * 4 * 4;
    float* a_dst   = (float*)ws; ws += (size_t)N * 4 * 4;
    int*   row_ptr = (int*)ws;   ws += (size_t)(N + 1) * 4;
    int*   cnt     = (int*)ws;   ws += (size_t)nchunk * NBUK_PAD * 4;
    unsigned* part = (unsigned*)ws; ws += (size_t)E * 4;
    int*   colsrc  = (int*)ws;   ws += (size_t)E * 4;
    int*   bt      = (int*)ws;   ws += 256 * 4;
    unsigned short* Whf = (unsigned short*)ws; ws += 8192 * 2;
    unsigned short* Wlf = (unsigned short*)ws; ws += 8192 * 2;
    unsigned short* Phf = (unsigned short*)ws; ws += 8192 * 2;
    unsigned short* Plf = (unsigned short*)ws; ws += 8192 * 2;
    float* pb2 = (float*)ws; ws += 128 * 4;

    // part2/xw interleave: one part2 block per (P-1) xw blocks
    int P = (nbXw + nchunk - 1) / nchunk + 1;
    int totalFused = nchunk * P;

    k_prep_part1<<<nchunk + nbPrep, 256, 0, stream>>>(W, bias, proj_w, proj_b,
                                                      Whf, Wlf, Phf, Plf, pb2,
                                                      dstIdx, cnt, E, nchunk);
    k_scanB1<<<256, 256, 0, stream>>>(cnt, bt, row_ptr, nchunk, N, E);
    k_part2_xw<<<totalFused, 256, 0, stream>>>(srcIdx, dstIdx, cnt, bt, part, E,
                                               x, Whf, Wlf, att_src, att_dst,
                                               xp, a_src, a_dst, N, P, nbXw);
    k_csr<<<NBUK, 256, 0, stream>>>(part, bt, row_ptr, colsrc, N);
    k_agg_proj<<<(N + 15) / 16, 256, 0, stream>>>(xp, a_src, a_dst, row_ptr, colsrc,
                                                  Phf, Plf, pb2, gamma, beta,
                                                  (float*)d_out, N);
}

// Round 19
// 78.716 us; speedup vs baseline: 1.0379x; 1.0379x over previous
//
#include <hip/hip_runtime.h>
#include <hip/hip_bf16.h>

// Fused GATConv + proj + LayerNorm + ReLU. N=50000, E=800000, F_IN=128, H=4, C=16, D=128.
// CSR build is ATOMIC-FREE at global scope (global atomics = 19G/s wall, rounds 6/8/9).
// CHUNK=2048 (8192 regressed, round 16). agg launch_bounds(256,6) (8 neutral, round 18).
//   k_prep_part1 : FUSED: per-chunk LDS histogram of dst>>8 + weight packing.
//                  W packed as FIVE 16-col tiles: 4 = W itself, 5th = [Was | Wad | 0]
//                  (Was[k][h]=sum_c W[k][hc]*att_src[h][c]) -> logits computed by MFMA.
//   k_scanB1     : per-bucket column scan over chunks -> per-(chunk,bucket) prefix + bt[]
//   k_part2_xw   : FUSED: (a) scatter edges into bucket runs, (b) xp/a_src/a_dst = x@[W|Was|Wad]
//                  split-bf16 MFMA, NO shfl epilogue.
//   k_csr        : per bucket: bb from bt (LDS scan) + exact-node histogram -> row_ptr/colsrc
//   k_agg_proj   : FUSED agg+proj+LN+ReLU (2x-unrolled gather: two u16x8 loads in flight)

#define LEAKY(x) ((x) > 0.f ? (x) : 0.2f * (x))
#define CHUNK 2048
#define NBUK_PAD 256

typedef __attribute__((ext_vector_type(8))) short bf16x8;
typedef __attribute__((ext_vector_type(8))) unsigned short u16x8;
typedef __attribute__((ext_vector_type(4))) float f32x4;

static __device__ __forceinline__ unsigned short f2bf_rne(float f) {
    unsigned u = __float_as_uint(f);
    return (unsigned short)((u + 0x7FFFu + ((u >> 16) & 1u)) >> 16);
}
static __device__ __forceinline__ float bf2f(unsigned short h) {
    return __uint_as_float(((unsigned)h) << 16);
}

// bid < nchunk: LDS histogram of one CHUNK-edge range by dst>>8.
// bid >= nchunk: weight packing. W frags idx [0,10240): 5 tiles x 4 kchunks;
// proj frags [10240,18432); pb2 [18432,18560).
__global__ __launch_bounds__(256) void k_prep_part1(
    const float* __restrict__ W, const float* __restrict__ bias,
    const float* __restrict__ att_src, const float* __restrict__ att_dst,
    const float* __restrict__ proj_w, const float* __restrict__ proj_b,
    unsigned short* __restrict__ Whf, unsigned short* __restrict__ Wlf,
    unsigned short* __restrict__ Phf, unsigned short* __restrict__ Plf,
    float* __restrict__ pb2,
    const int* __restrict__ dst, int* __restrict__ cnt, int E, int nchunk)
{
    int bid = blockIdx.x, t = threadIdx.x;
    if (bid < nchunk) {
        __shared__ int hist[NBUK_PAD];
        hist[t] = 0;
        __syncthreads();
        int e0 = bid * CHUNK;
#pragma unroll
        for (int i = 0; i < CHUNK / 256; i++) {
            int e = e0 + i * 256 + t;
            if (e < E) atomicAdd(&hist[dst[e] >> 8], 1);   // LDS atomic
        }
        __syncthreads();
        cnt[bid * NBUK_PAD + t] = hist[t];
        return;
    }
    int idx = (bid - nchunk) * 256 + t;
    if (idx < 10240) {
        int j = idx & 7, lane = (idx >> 3) & 63, ts = idx >> 9;   // ts 0..19
        int t4 = ts >> 2, s = ts & 3;
        int k = s * 32 + ((lane >> 4) << 3) + j;
        float w = 0.f;
        if (t4 < 4) {
            int n = t4 * 16 + (lane & 15);
            w = W[k * 64 + n];
        } else {
            int c8 = lane & 15;           // col within 5th tile
            if (c8 < 8) {
                const float* av = (c8 < 4) ? att_src : att_dst;
                int hh = c8 & 3;
                float sacc = 0.f;
                for (int c = 0; c < 16; c++)
                    sacc += W[k * 64 + hh * 16 + c] * av[hh * 16 + c];
                w = sacc;
            }
        }
        unsigned short wh = f2bf_rne(w);
        Whf[idx] = wh;
        Wlf[idx] = f2bf_rne(w - bf2f(wh));
    } else if (idx < 18432) {
        int i2 = idx - 10240;
        int j = i2 & 7, lane = (i2 >> 3) & 63, ts = i2 >> 9;
        int tt = ts >> 1, s = ts & 1;
        int k = s * 32 + ((lane >> 4) << 3) + j;
        int d = tt * 16 + (lane & 15);
        float w = proj_w[d * 64 + k];
        unsigned short wh = f2bf_rne(w);
        Phf[i2] = wh;
        Plf[i2] = f2bf_rne(w - bf2f(wh));
    } else if (idx < 18432 + 128) {
        int d = idx - 18432;
        float s = proj_b[d];
        for (int j = 0; j < 64; j++) s += bias[j] * proj_w[d * 64 + j];
        pb2[d] = s;
    }
}

// Per-bucket column scan over chunks (nchunk <= 512). Emits bucket totals bt[].
__global__ __launch_bounds__(256) void k_scanB1(int* __restrict__ cnt, int* __restrict__ bt,
                                                int* __restrict__ row_ptr,
                                                int nchunk, int n_nodes, int E)
{
    __shared__ int sh[256];
    int t = threadIdx.x, b = blockIdx.x;
    int v0 = (t < nchunk) ? cnt[t * NBUK_PAD + b] : 0;
    int v1 = (t + 256 < nchunk) ? cnt[(t + 256) * NBUK_PAD + b] : 0;
    sh[t] = v0; __syncthreads();
    for (int off = 1; off < 256; off <<= 1) {
        int u = (t >= off) ? sh[t - off] : 0;
        __syncthreads();
        sh[t] += u;
        __syncthreads();
    }
    int incl0 = sh[t], tot0 = sh[255];
    __syncthreads();
    sh[t] = v1; __syncthreads();
    for (int off = 1; off < 256; off <<= 1) {
        int u = (t >= off) ? sh[t - off] : 0;
        __syncthreads();
        sh[t] += u;
        __syncthreads();
    }
    int incl1 = sh[t] + tot0;
    if (t < nchunk) cnt[t * NBUK_PAD + b] = incl0 - v0;
    if (t + 256 < nchunk) cnt[(t + 256) * NBUK_PAD + b] = incl1 - v1;
    if (t == 255) bt[b] = incl1;
    if (b == 0 && t == 0) row_ptr[n_nodes] = E;
}

// FUSED part2 + xw. Every P-th block scatters one CHUNK-edge range into bucket runs;
// other blocks do a 64-node xw tile (xp + logits, all via MFMA; no shfl epilogue).
__global__ __launch_bounds__(256) void k_part2_xw(
    const int* __restrict__ src, const int* __restrict__ dst,
    const int* __restrict__ cnt, const int* __restrict__ bt,
    unsigned* __restrict__ part, int E,
    const float* __restrict__ x,
    const unsigned short* __restrict__ Whf, const unsigned short* __restrict__ Wlf,
    unsigned short* __restrict__ xp, float* __restrict__ a_src, float* __restrict__ a_dst,
    int n_nodes, int P, int nbXw)
{
    __shared__ float xs[64][132];          // 33.8 KB (xw path)
    __shared__ int bases[NBUK_PAD];        // part2 path
    __shared__ int sh[256];
    int bid = blockIdx.x, t = threadIdx.x;
    if (bid % P == P - 1) {
        int blk = bid / P;
        int v = bt[t];
        sh[t] = v; __syncthreads();
        for (int off = 1; off < 256; off <<= 1) {
            int u = (t >= off) ? sh[t - off] : 0;
            __syncthreads();
            sh[t] += u;
            __syncthreads();
        }
        bases[t] = cnt[blk * NBUK_PAD + t] + (sh[t] - v);
        __syncthreads();
        int e0 = blk * CHUNK;
#pragma unroll
        for (int i = 0; i < CHUNK / 256; i++) {
            int e = e0 + i * 256 + t;
            if (e < E) {
                int d = dst[e];
                int s = src[e];
                int pos = atomicAdd(&bases[d >> 8], 1);   // LDS atomic
                part[pos] = ((unsigned)s << 8) | (unsigned)(d & 255);
            }
        }
        return;
    }
    // ---- xw path ----
    int xb = bid - bid / P;
    if (xb >= nbXw) return;
    int xbase = xb * 64;
    for (int i = t; i < 64 * 32; i += 256) {
        int r = i >> 5, c = (i & 31) << 2;
        int gr = xbase + r; if (gr >= n_nodes) gr = n_nodes - 1;
        *(float4*)&xs[r][c] = *(const float4*)(x + (size_t)gr * 128 + c);
    }
    __syncthreads();
    int w = t >> 6, lane = t & 63;
    int mbase = xbase + w * 16;
    int mrow = lane & 15, kg = lane >> 4;
    int lrow = w * 16 + mrow;

    bf16x8 ah[4], al[4];
#pragma unroll
    for (int s = 0; s < 4; s++) {
        float4 v0 = *(const float4*)&xs[lrow][s * 32 + kg * 8];
        float4 v1 = *(const float4*)&xs[lrow][s * 32 + kg * 8 + 4];
        float f[8] = {v0.x, v0.y, v0.z, v0.w, v1.x, v1.y, v1.z, v1.w};
#pragma unroll
        for (int j = 0; j < 8; j++) {
            unsigned short h = f2bf_rne(f[j]);
            ah[s][j] = (short)h;
            al[s][j] = (short)f2bf_rne(f[j] - bf2f(h));
        }
    }

    f32x4 acc[5];
#pragma unroll
    for (int tt = 0; tt < 5; tt++) acc[tt] = (f32x4){0.f, 0.f, 0.f, 0.f};
#pragma unroll
    for (int tt = 0; tt < 5; tt++) {
#pragma unroll
        for (int s = 0; s < 4; s++) {
            size_t fi = (size_t)(((tt * 4 + s) * 64 + lane) * 8);
            bf16x8 bh = *(const bf16x8*)(Whf + fi);
            bf16x8 bl = *(const bf16x8*)(Wlf + fi);
            acc[tt] = __builtin_amdgcn_mfma_f32_16x16x32_bf16(ah[s], bh, acc[tt], 0, 0, 0);
            acc[tt] = __builtin_amdgcn_mfma_f32_16x16x32_bf16(ah[s], bl, acc[tt], 0, 0, 0);
            acc[tt] = __builtin_amdgcn_mfma_f32_16x16x32_bf16(al[s], bh, acc[tt], 0, 0, 0);
        }
    }

    // D layout: col=lane&15, row=(lane>>4)*4+reg. Tiles 0-3 -> xp; tile 4 -> logits.
#pragma unroll
    for (int tt = 0; tt < 4; tt++) {
#pragma unroll
        for (int r = 0; r < 4; r++) {
            int n2 = mbase + kg * 4 + r;
            if (n2 < n_nodes) xp[(size_t)n2 * 64 + tt * 16 + mrow] = f2bf_rne(acc[tt][r]);
        }
    }
#pragma unroll
    for (int r = 0; r < 4; r++) {
        int n2 = mbase + kg * 4 + r;
        if (n2 < n_nodes) {
            float v = acc[4][r];
            if (mrow < 4)      a_src[n2 * 4 + mrow] = v;
            else if (mrow < 8) a_dst[n2 * 4 + (mrow - 4)] = v;
        }
    }
}

// One block per bucket: bb from bt (LDS scan), exact-node histogram + scan -> row_ptr/colsrc.
__global__ __launch_bounds__(256) void k_csr(const unsigned* __restrict__ part, const int* __restrict__ bt,
                                             int* __restrict__ row_ptr, int* __restrict__ colsrc,
                                             int n_nodes)
{
    __shared__ int hist[256], off[256], sh[256];
    int t = threadIdx.x, b = blockIdx.x;
    int v = bt[t];
    sh[t] = v; __syncthreads();
    for (int o = 1; o < 256; o <<= 1) {
        int u = (t >= o) ? sh[t - o] : 0;
        __syncthreads();
        sh[t] += u;
        __syncthreads();
    }
    int e0 = (b > 0) ? sh[b - 1] : 0;
    int e1 = sh[b];
    __syncthreads();
    int m = e1 - e0;
    hist[t] = 0;
    __syncthreads();
    for (int i = t; i < m; i += 256)
        atomicAdd(&hist[part[e0 + i] & 255u], 1);     // LDS atomic
    __syncthreads();
    int hv = hist[t];
    sh[t] = hv; __syncthreads();
    for (int o = 1; o < 256; o <<= 1) {
        int u = (t >= o) ? sh[t - o] : 0;
        __syncthreads();
        sh[t] += u;
        __syncthreads();
    }
    int excl = sh[t] - hv;
    off[t] = excl;
    int node = b * 256 + t;
    if (node < n_nodes) row_ptr[node] = e0 + excl;
    __syncthreads();
    for (int i = t; i < m; i += 256) {
        unsigned u = part[e0 + i];
        int pos = atomicAdd(&off[u & 255u], 1);       // LDS atomic
        colsrc[e0 + pos] = (int)(u >> 8);
    }
}

// FUSED aggregation + projection + LayerNorm + ReLU. Block = 16 nodes, 4 waves.
// Phase 1 (per wave): 4 nodes, one at a time; gather loop 2x-unrolled (two u16x8 loads
//   in flight). Phase 2: proj d-tiles split across waves (2 each, 8 MFMA/wave), LN via
//   cross-wave LDS partials, ReLU, store.
__global__ __launch_bounds__(256, 6) void k_agg_proj(
    const unsigned short* __restrict__ xp, const float* __restrict__ a_src, const float* __restrict__ a_dst,
    const int* __restrict__ row_ptr, const int* __restrict__ colsrc,
    const unsigned short* __restrict__ Phf, const unsigned short* __restrict__ Plf,
    const float* __restrict__ pb2, const float* __restrict__ gamma, const float* __restrict__ beta,
    float* __restrict__ out, int n_nodes)
{
    __shared__ int   sstage[4][64];            // 1 KB
    __shared__ float alpha_s[4][64][4];        // 4 KB
    __shared__ unsigned short rowbuf[16][72];  // 2.25 KB (144B rows, 16B aligned)
    __shared__ float pS[4][16], pQ[4][16];     // 0.5 KB
    __shared__ float pb_s[128], g_s[128], b_s[128];
    int t = threadIdx.x, w = t >> 6, lane = t & 63;
    if (t < 128) { pb_s[t] = pb2[t]; g_s[t] = gamma[t]; b_s[t] = beta[t]; }
    int cgrp = lane & 7;      // channels 8*cgrp .. 8*cgrp+7
    int eoct = lane >> 3;     // edge slot 0..7
    int h = cgrp >> 1;        // head of my 8 channels
    int nb16 = blockIdx.x * 16;

    // ---- phase 1: aggregate 4 nodes per wave ----
    for (int i = 0; i < 4; i++) {
        int n = nb16 + w * 4 + i;
        int nl = w * 4 + i;
        float acc[8] = {0.f,0.f,0.f,0.f,0.f,0.f,0.f,0.f};
        float den = 0.f;
        if (n < n_nodes) {
            int rp0 = row_ptr[n], rp1 = row_ptr[n + 1];
            float4 ad4 = *(const float4*)&a_dst[(size_t)n * 4];
            for (int base = rp0; base < rp1; base += 64) {
                int cnt = rp1 - base; if (cnt > 64) cnt = 64;
                int s = 0;
                float4 p = make_float4(0.f, 0.f, 0.f, 0.f);
                if (lane < cnt) {
                    s = colsrc[base + lane];
                    float4 as4 = *(const float4*)&a_src[(size_t)s * 4];
                    p.x = __expf(LEAKY(as4.x + ad4.x));
                    p.y = __expf(LEAKY(as4.y + ad4.y));
                    p.z = __expf(LEAKY(as4.z + ad4.z));
                    p.w = __expf(LEAKY(as4.w + ad4.w));
                }
                sstage[w][lane] = s;
                *(float4*)&alpha_s[w][lane][0] = p;
                // same-wave LDS write->read is in-order; no barrier needed
                int iters = (cnt + 7) >> 3;
                int it = 0;
                // 2x unroll: issue both gathers before consuming either (2x MLP).
                for (; it + 2 <= iters; it += 2) {
                    int j0 = (it << 3) + eoct;
                    int j1 = j0 + 8;
                    int sj0 = sstage[w][j0];
                    int sj1 = sstage[w][j1];
                    float aj0 = alpha_s[w][j0][h];
                    float aj1 = alpha_s[w][j1][h];
                    u16x8 v0 = *(const u16x8*)(xp + (size_t)((unsigned)sj0 * 64u + (cgrp << 3)));
                    u16x8 v1 = *(const u16x8*)(xp + (size_t)((unsigned)sj1 * 64u + (cgrp << 3)));
                    den += aj0;
#pragma unroll
                    for (int q = 0; q < 8; q++) acc[q] += aj0 * bf2f(v0[q]);
                    den += aj1;
#pragma unroll
                    for (int q = 0; q < 8; q++) acc[q] += aj1 * bf2f(v1[q]);
                }
                if (it < iters) {
                    int j = (it << 3) + eoct;
                    int sj = sstage[w][j];
                    float aj = alpha_s[w][j][h];
                    u16x8 v = *(const u16x8*)(xp + (size_t)((unsigned)sj * 64u + (cgrp << 3)));
                    den += aj;
#pragma unroll
                    for (int q = 0; q < 8; q++) acc[q] += aj * bf2f(v[q]);
                }
            }
#pragma unroll
            for (int q = 0; q < 8; q++) {
                acc[q] += __shfl_xor(acc[q], 8);
                acc[q] += __shfl_xor(acc[q], 16);
                acc[q] += __shfl_xor(acc[q], 32);
            }
            den += __shfl_xor(den, 8);
            den += __shfl_xor(den, 16);
            den += __shfl_xor(den, 32);
        }
        if (eoct == 0) {
            float inv = 1.f / (den + 1e-16f);
            u16x8 o;
#pragma unroll
            for (int q = 0; q < 8; q++) o[q] = f2bf_rne(acc[q] * inv);
            *(u16x8*)&rowbuf[nl][cgrp << 3] = o;
        }
    }
    __syncthreads();

    // ---- phase 2: projection. wave w covers d-tiles {2w, 2w+1} for all 16 nodes ----
    int mrow = lane & 15, kg = lane >> 4;
    bf16x8 ah[2];
#pragma unroll
    for (int s = 0; s < 2; s++) {
        ah[s] = *(const bf16x8*)&rowbuf[mrow][s * 32 + kg * 8];
    }
    f32x4 acc2[2];
#pragma unroll
    for (int ttl = 0; ttl < 2; ttl++) acc2[ttl] = (f32x4){0.f, 0.f, 0.f, 0.f};
#pragma unroll
    for (int ttl = 0; ttl < 2; ttl++) {
        int tt = w * 2 + ttl;
#pragma unroll
        for (int s = 0; s < 2; s++) {
            size_t fi = (size_t)(((tt * 2 + s) * 64 + lane) * 8);
            bf16x8 bh = *(const bf16x8*)(Phf + fi);
            bf16x8 bl = *(const bf16x8*)(Plf + fi);
            acc2[ttl] = __builtin_amdgcn_mfma_f32_16x16x32_bf16(ah[s], bh, acc2[ttl], 0, 0, 0);
            acc2[ttl] = __builtin_amdgcn_mfma_f32_16x16x32_bf16(ah[s], bl, acc2[ttl], 0, 0, 0);
        }
    }
    // D layout: node_row = kg*4 + r, d = tt*16 + mrow. LN partials per node over this
    // wave's 32 d-channels; cross-wave combine via LDS.
    float vv[2][4];
#pragma unroll
    for (int r = 0; r < 4; r++) {
        float S = 0.f, Q = 0.f;
#pragma unroll
        for (int ttl = 0; ttl < 2; ttl++) {
            int tt = w * 2 + ttl;
            float v = acc2[ttl][r] + pb_s[tt * 16 + mrow];
            vv[ttl][r] = v;
            S += v;
            Q += v * v;
        }
#pragma unroll
        for (int off = 8; off; off >>= 1) {
            S += __shfl_xor(S, off);
            Q += __shfl_xor(Q, off);
        }
        if (mrow == 0) { pS[w][kg * 4 + r] = S; pQ[w][kg * 4 + r] = Q; }
    }
    __syncthreads();
#pragma unroll
    for (int r = 0; r < 4; r++) {
        int nl = kg * 4 + r;
        int nr = nb16 + nl;
        float S = pS[0][nl] + pS[1][nl] + pS[2][nl] + pS[3][nl];
        float Q = pQ[0][nl] + pQ[1][nl] + pQ[2][nl] + pQ[3][nl];
        float mu  = S * (1.f / 128.f);
        float var = Q * (1.f / 128.f) - mu * mu;
        float inv = rsqrtf(var + 1e-5f);
        if (nr < n_nodes) {
#pragma unroll
            for (int ttl = 0; ttl < 2; ttl++) {
                int d = (w * 2 + ttl) * 16 + mrow;
                float o = fmaxf((vv[ttl][r] - mu) * inv * g_s[d] + b_s[d], 0.f);
                out[(size_t)nr * 128 + d] = o;
            }
        }
    }
}

extern "C" void kernel_launch(void* const* d_in, const int* in_sizes, int n_in,
                              void* d_out, int out_size, void* d_ws, size_t ws_size,
                              hipStream_t stream)
{
    const float* x       = (const float*)d_in[0];
    const int*   ei      = (const int*)  d_in[1];
    const float* W       = (const float*)d_in[2];
    const float* att_src = (const float*)d_in[3];
    const float* att_dst = (const float*)d_in[4];
    const float* bias    = (const float*)d_in[5];
    const float* proj_w  = (const float*)d_in[6];
    const float* proj_b  = (const float*)d_in[7];
    const float* gamma   = (const float*)d_in[8];
    const float* beta    = (const float*)d_in[9];

    int N = in_sizes[0] / 128;
    int E = in_sizes[1] / 2;
    const int* srcIdx = ei;
    const int* dstIdx = ei + E;

    int nchunk = (E + CHUNK - 1) / CHUNK;          // edge chunks
    int NBUK   = (N + 255) / 256;                  // node buckets
    int nbXw   = (N + 63) / 64;
    int nbPrep = (18560 + 255) / 256;

    char* ws = (char*)d_ws;
    unsigned short* xp = (unsigned short*)ws; ws += (size_t)N * 64 * 2;
    float* a_src   = (float*)ws; ws += (size_t)N * 4 * 4;
    float* a_dst   = (float*)ws; ws += (size_t)N * 4 * 4;
    int*   row_ptr = (int*)ws;   ws += (size_t)(N + 1) * 4;
    int*   cnt     = (int*)ws;   ws += (size_t)nchunk * NBUK_PAD * 4;
    unsigned* part = (unsigned*)ws; ws += (size_t)E * 4;
    int*   colsrc  = (int*)ws;   ws += (size_t)E * 4;
    int*   bt      = (int*)ws;   ws += 256 * 4;
    unsigned short* Whf = (unsigned short*)ws; ws += 10240 * 2;
    unsigned short* Wlf = (unsigned short*)ws; ws += 10240 * 2;
    unsigned short* Phf = (unsigned short*)ws; ws += 8192 * 2;
    unsigned short* Plf = (unsigned short*)ws; ws += 8192 * 2;
    float* pb2 = (float*)ws; ws += 128 * 4;

    // part2/xw interleave: one part2 block per (P-1) xw blocks
    int P = (nbXw + nchunk - 1) / nchunk + 1;
    int totalFused = nchunk * P;

    k_prep_part1<<<nchunk + nbPrep, 256, 0, stream>>>(W, bias, att_src, att_dst,
                                                      proj_w, proj_b,
                                                      Whf, Wlf, Phf, Plf, pb2,
                                                      dstIdx, cnt, E, nchunk);
    k_scanB1<<<256, 256, 0, stream>>>(cnt, bt, row_ptr, nchunk, N, E);
    k_part2_xw<<<totalFused, 256, 0, stream>>>(srcIdx, dstIdx, cnt, bt, part, E,
                                               x, Whf, Wlf,
                                               xp, a_src, a_dst, N, P, nbXw);
    k_csr<<<NBUK, 256, 0, stream>>>(part, bt, row_ptr, colsrc, N);
    k_agg_proj<<<(N + 15) / 16, 256, 0, stream>>>(xp, a_src, a_dst, row_ptr, colsrc,
                                                  Phf, Plf, pb2, gamma, beta,
                                                  (float*)d_out, N);
}